// Round 11
// baseline (872.577 us; speedup 1.0000x reference)
//
#include <hip/hip_runtime.h>

#define HW 4096
#define S_E ((size_t)4 * 256 * 4096)   // elems in one (B,256,64,64) tensor

using f16   = _Float16;
using f16x8 = __attribute__((ext_vector_type(8))) _Float16;
using f32x4 = __attribute__((ext_vector_type(4))) float;

__device__ __forceinline__ float hswish(float x) {
  float r = fminf(fmaxf(x + 3.0f, 0.0f), 6.0f);
  return x * r * (1.0f / 6.0f);
}

__device__ __forceinline__ void atomic_add_f32(float* p, float v) {
  __hip_atomic_fetch_add(p, v, __ATOMIC_RELAXED, __HIP_MEMORY_SCOPE_AGENT);
}

__global__ __launch_bounds__(256) void zero_buf4(float4* __restrict__ p, int n4) {
  int i = blockIdx.x * 256 + threadIdx.x;
  if (i < n4) p[i] = make_float4(0.f, 0.f, 0.f, 0.f);
}

// fp32 -> f16 hi/lo planes (x = hi + lo, ~22 significand bits)
__global__ __launch_bounds__(256) void cvt_planes(
    const float* __restrict__ in, f16* __restrict__ hi, f16* __restrict__ lo, int n4)
{
  int i = blockIdx.x * 256 + threadIdx.x;
  if (i >= n4) return;
  float4 v = ((const float4*)in)[i];
  const float* f = &v.x;
  unsigned int hw[2], lw[2];
  #pragma unroll
  for (int j = 0; j < 2; ++j) {
    f16 h0 = (f16)f[2 * j], h1 = (f16)f[2 * j + 1];
    f16 l0 = (f16)(f[2 * j] - (float)h0), l1 = (f16)(f[2 * j + 1] - (float)h1);
    hw[j] = (unsigned int)__builtin_bit_cast(unsigned short, h0) |
            ((unsigned int)__builtin_bit_cast(unsigned short, h1) << 16);
    lw[j] = (unsigned int)__builtin_bit_cast(unsigned short, l0) |
            ((unsigned int)__builtin_bit_cast(unsigned short, l1) << 16);
  }
  *(uint2*)(hi + 4 * (size_t)i) = make_uint2(hw[0], hw[1]);
  *(uint2*)(lo + 4 * (size_t)i) = make_uint2(lw[0], lw[1]);
}

// fp32 weights [CO][K] -> MFMA-fragment-ordered hi/lo planes:
// chunk g = (ct*(K/32) + kq)*64 + lane holds w[ct*16 + (lane&15)][kq*32 + (lane>>4)*8 + 0..7].
// In the GEMM, a wave's fragment load becomes base + lane*16B -> one contiguous 1KB burst.
__global__ __launch_bounds__(256) void cvt_wfrag(
    const float* __restrict__ in, f16* __restrict__ hi, f16* __restrict__ lo,
    int K, int nch)
{
  int g = blockIdx.x * 256 + threadIdx.x;
  if (g >= nch) return;
  int lane = g & 63;
  int kq   = (g >> 6) % (K >> 5);
  int ct   = g / ((K >> 5) << 6);
  const float* src = in + (size_t)(ct * 16 + (lane & 15)) * K
                        + kq * 32 + (lane >> 4) * 8;
  unsigned short hv[8], lv[8];
  #pragma unroll
  for (int j = 0; j < 8; ++j) {
    float v = src[j];
    f16 h = (f16)v;
    hv[j] = __builtin_bit_cast(unsigned short, h);
    lv[j] = __builtin_bit_cast(unsigned short, (f16)(v - (float)h));
  }
  *(uint4*)(hi + (size_t)g * 8) = *(const uint4*)hv;
  *(uint4*)(lo + (size_t)g * 8) = *(const uint4*)lv;
}

// f16x3 split MFMA 1x1-conv GEMM — R8 version (fragment-ordered weights), KS=64.
template<int KS>
__global__ __launch_bounds__(256) void gemm_mfma(
    const f16* __restrict__ xhi0, const f16* __restrict__ xlo0,
    const f16* __restrict__ xhi1, const f16* __restrict__ xlo1,
    const f16* __restrict__ whi, const f16* __restrict__ wlo,
    float* __restrict__ out, f16* __restrict__ ohi, f16* __restrict__ olo,
    const float* __restrict__ scale, const float* __restrict__ bias,
    int K, int k0, int CO, int epi)
{
  constexpr int ST = KS + 4;       // f16 row stride in LDS
  constexpr int NC = KS / 32;      // 32-k chunks per staged step
  __shared__ f16 Bh[64 * ST];
  __shared__ f16 Bl[64 * ST];
  const int p0  = blockIdx.x * 64;
  const int co0 = blockIdx.y * 128;
  const int b   = blockIdx.z;
  const int tid = threadIdx.x;
  const int lane = tid & 63;
  const int wave = tid >> 6;
  const int wc = wave & 1, wp = wave >> 1;
  const int k1 = K - k0;

  const int tt    = tid & 127;
  const int kbase = (tt >> 3) * 2;
  const int poct  = (tt & 7) * 8;
  const f16* x0 = (tid < 128) ? xhi0 : xlo0;
  const f16* x1 = (tid < 128) ? xhi1 : xlo1;
  f16* Bp = (tid < 128) ? Bh : Bl;

  const int q  = lane >> 4;
  const int ln = lane & 15;
  const int kq5 = K >> 5;                       // K/32
  const int ctb = (co0 >> 4) + wc * 4;          // fragment row-tile base

  f32x4 acc[4][2];
  #pragma unroll
  for (int im = 0; im < 4; ++im)
    #pragma unroll
    for (int in = 0; in < 2; ++in)
      acc[im][in] = (f32x4){0.f, 0.f, 0.f, 0.f};

  auto gaddr = [&](int kg) -> const f16* {
    return (kg < k0) ? x0 + ((size_t)b * k0 + kg) * HW
                     : x1 + ((size_t)b * k1 + (kg - k0)) * HW;
  };

  uint4 g0[NC], g1[NC];
  #pragma unroll
  for (int c = 0; c < NC; ++c) {
    const f16* x = gaddr(c * 32 + kbase);
    g0[c] = *(const uint4*)(x + p0 + poct);
    g1[c] = *(const uint4*)(x + HW + p0 + poct);
  }

  for (int kt = 0; kt < K; kt += KS) {
    #pragma unroll
    for (int c = 0; c < NC; ++c) {
      const unsigned short* u0 = (const unsigned short*)&g0[c];
      const unsigned short* u1 = (const unsigned short*)&g1[c];
      #pragma unroll
      for (int i = 0; i < 8; ++i) {
        unsigned int d = (unsigned int)u0[i] | ((unsigned int)u1[i] << 16);
        *(unsigned int*)(Bp + (poct + i) * ST + c * 32 + kbase) = d;
      }
    }
    __syncthreads();
    if (kt + KS < K) {
      #pragma unroll
      for (int c = 0; c < NC; ++c) {
        const f16* x = gaddr(kt + KS + c * 32 + kbase);
        g0[c] = *(const uint4*)(x + p0 + poct);
        g1[c] = *(const uint4*)(x + HW + p0 + poct);
      }
    }
    #pragma unroll
    for (int c = 0; c < NC; ++c) {
      f16x8 bh[2], bl[2];
      #pragma unroll
      for (int in = 0; in < 2; ++in) {
        const f16* fp = &Bh[(wp * 32 + in * 16 + ln) * ST + c * 32 + q * 8];
        const f16* gp = &Bl[(wp * 32 + in * 16 + ln) * ST + c * 32 + q * 8];
        ((uint2*)&bh[in])[0] = *(const uint2*)fp;
        ((uint2*)&bh[in])[1] = *(const uint2*)(fp + 4);
        ((uint2*)&bl[in])[0] = *(const uint2*)gp;
        ((uint2*)&bl[in])[1] = *(const uint2*)(gp + 4);
      }
      const int kq = (kt + c * 32) >> 5;
      #pragma unroll
      for (int im = 0; im < 4; ++im) {
        size_t wofs = (((size_t)(ctb + im) * kq5 + kq) << 9) + lane * 8;
        f16x8 ah = *(const f16x8*)(whi + wofs);
        f16x8 al = *(const f16x8*)(wlo + wofs);
        #pragma unroll
        for (int in = 0; in < 2; ++in) {
          acc[im][in] = __builtin_amdgcn_mfma_f32_16x16x32_f16(ah, bh[in], acc[im][in], 0, 0, 0);
          acc[im][in] = __builtin_amdgcn_mfma_f32_16x16x32_f16(ah, bl[in], acc[im][in], 0, 0, 0);
          acc[im][in] = __builtin_amdgcn_mfma_f32_16x16x32_f16(al, bh[in], acc[im][in], 0, 0, 0);
        }
      }
    }
    __syncthreads();
  }

  #pragma unroll
  for (int im = 0; im < 4; ++im) {
    #pragma unroll
    for (int in = 0; in < 2; ++in) {
      int p = p0 + wp * 32 + in * 16 + ln;
      #pragma unroll
      for (int r = 0; r < 4; ++r) {
        int co = co0 + wc * 64 + im * 16 + q * 4 + r;
        float v = acc[im][in][r];
        if (epi == 1)      v = v * scale[co] + bias[co];
        else if (epi == 2) v = hswish(v * scale[co] + bias[co]);
        else if (epi == 3) v = hswish(v + bias[co]);
        size_t idx = ((size_t)b * CO + co) * HW + p;
        if (out) out[idx] = v;
        else {
          f16 h = (f16)v;
          ohi[idx] = h;
          olo[idx] = (f16)(v - (float)h);
        }
      }
    }
  }
}

// LDS-tiled depthwise 3x3, pad 1. One block per (b,c). pmode 1 -> f16 planes out.
__global__ __launch_bounds__(256) void dwconv3(
    const float* __restrict__ in, const float* __restrict__ w,
    float* __restrict__ out, f16* __restrict__ ohi, f16* __restrict__ olo,
    const float* __restrict__ scale, const float* __restrict__ bias,
    int Cmask, int epi, int pmode)
{
  __shared__ float tl[66 * 66];
  const int bc = blockIdx.x;
  const int c  = bc & Cmask;
  const float* src = in + (size_t)bc * HW;
  const int t = threadIdx.x;
  for (int i = t; i < 66 * 66; i += 256) {
    int r = i / 66, cc = i - r * 66;
    int gy = r - 1, gx = cc - 1;
    float v = 0.0f;
    if (gy >= 0 && gy < 64 && gx >= 0 && gx < 64) v = src[(gy << 6) + gx];
    tl[i] = v;
  }
  const float* wp = w + c * 9;
  float w00 = wp[0], w01 = wp[1], w02 = wp[2];
  float w10 = wp[3], w11 = wp[4], w12 = wp[5];
  float w20 = wp[6], w21 = wp[7], w22 = wp[8];
  float g = (epi == 2) ? scale[c] : 1.0f;
  float bb = bias[c];
  __syncthreads();
  #pragma unroll 4
  for (int j = 0; j < 16; ++j) {
    int p = j * 256 + t;
    int y = p >> 6, x = p & 63;
    const float* bp = &tl[y * 66 + x];
    float s;
    s = w00 * bp[0]        + w01 * bp[1]        + w02 * bp[2];
    s = fmaf(w10, bp[66],    fmaf(w11, bp[67],    fmaf(w12, bp[68],  s)));
    s = fmaf(w20, bp[132],   fmaf(w21, bp[133],   fmaf(w22, bp[134], s)));
    float v = (epi == 2) ? hswish(s * g + bb) : hswish(s + bb);
    size_t idx = (size_t)bc * HW + p;
    if (pmode) {
      f16 h = (f16)v;
      ohi[idx] = h;
      olo[idx] = (f16)(v - (float)h);
    } else {
      out[idx] = v;
    }
  }
}

// Fused dw5x5(pad2) + grouped 1x1 (32->32 per group).
// R10: weights read directly from global (wave-uniform -> scalar path).
template<int TR>
__global__ __launch_bounds__(256) void agg_fused(
    const float* __restrict__ in, const float* __restrict__ dw,
    const float* __restrict__ pw, float* __restrict__ out, int C)
{
  constexpr int RH = TR + 4;            // tile rows incl. halo
  constexpr int NR = TR / 4;            // row-sets per thread
  __shared__ float in_t[8 * RH * 68];
  const int g = blockIdx.x, b = blockIdx.y, tile = blockIdx.z;
  const int t = threadIdx.x;
  const int y0 = tile * TR;
  const float* src = in + ((size_t)b * C + g * 32) * HW;
  const float* dwg = dw + (size_t)g * 800;
  const float* pwg = pw + (size_t)g * 1024;

  const int x = t & 63, yl = t >> 6;
  float acc[NR][32] = {};

  for (int ph = 0; ph < 4; ++ph) {
    __syncthreads();
    constexpr int T4 = 8 * RH * 16;
    for (int i = t; i < T4; i += 256) {
      int qq = i & 15;
      int rid = i >> 4;
      int ch = rid / RH, r = rid - ch * RH;
      int gy = y0 - 2 + r;
      float4 v = make_float4(0.f, 0.f, 0.f, 0.f);
      if (gy >= 0 && gy < 64)
        v = *(const float4*)(src + (size_t)(ph * 8 + ch) * HW + (gy << 6) + (qq << 2));
      *(float4*)&in_t[(ch * RH + r) * 68 + 2 + (qq << 2)] = v;
    }
    for (int i = t; i < 8 * RH * 4; i += 256) {
      int side = i & 3;
      int rid = i >> 2;
      int col = (side < 2) ? side : 64 + side;
      in_t[rid * 68 + col] = 0.0f;
    }
    __syncthreads();
    for (int cl = 0; cl < 8; ++cl) {
      int ci = ph * 8 + cl;
      const float* bp = &in_t[(cl * RH) * 68 + 2 + x];
      const float* wv = dwg + ci * 25;           // uniform addr -> s_load
      float d[NR] = {};
      #pragma unroll
      for (int k = 0; k < 25; ++k) {
        int dy = k / 5, dx = (k % 5) - 2;
        float w = wv[k];
        #pragma unroll
        for (int r = 0; r < NR; ++r)
          d[r] = fmaf(w, bp[(yl + r * 4 + dy) * 68 + dx], d[r]);
      }
      #pragma unroll
      for (int m = 0; m < 32; ++m) {
        float w = pwg[m * 32 + ci];              // uniform addr -> s_load
        #pragma unroll
        for (int r = 0; r < NR; ++r)
          acc[r][m] = fmaf(w, d[r], acc[r][m]);
      }
    }
  }
  float* dst = out + ((size_t)b * C + g * 32) * HW + y0 * 64;
  #pragma unroll
  for (int m = 0; m < 32; ++m) {
    #pragma unroll
    for (int r = 0; r < NR; ++r)
      dst[(size_t)m * HW + ((yl + r * 4) << 6) + x] = acc[r][m];
  }
}

// Attention phase A. R11: red buffer ALIASED onto the staging tile (it is only
// needed after compute finishes reading the tile; extra barrier separates the
// uses) -> LDS 49.7 -> 33.3 KB (4 blocks/CU), and __launch_bounds__(256,4)
// caps VGPR at 128 so 4 waves/SIMD are actually schedulable. Same arithmetic,
// same order -> bit-identical numerics.
__global__ __launch_bounds__(256, 4) void att_ctx(
    const float* __restrict__ kv, const float* __restrict__ kvs,
    float* __restrict__ ctxbuf)
{
  __shared__ float tile[64 * 128];   // staging; reused as red[4*1056] after compute
  float* red = tile;
  const int head  = blockIdx.x;
  const int b     = blockIdx.y;
  const int slice = blockIdx.z & 31;
  const int z     = blockIdx.z >> 5;
  const int tid   = threadIdx.x;
  const int lane  = tid & 63;
  const int wave  = tid >> 6;
  const int td = lane & 7, te = lane >> 3;

  const float* kvsrc = (head < 8)
      ? kv  + ((size_t)b * 1024 + z * 512 + head * 64) * HW
      : kvs + ((size_t)b * 1024 + z * 512 + (head - 8) * 64) * HW;
  const int n0 = slice * 128;

  #pragma unroll
  for (int j = 0; j < 8; ++j) {
    int slot = j * 256 + tid;          // 2048 float4 slots
    int ch = slot >> 5;                // 32 blocks per row
    int nb = slot & 31;
    float4 v = *(const float4*)(kvsrc + (size_t)ch * HW + n0 + (nb << 2));
    if (ch < 32) {
      v.x = fmaxf(v.x, 0.0f); v.y = fmaxf(v.y, 0.0f);
      v.z = fmaxf(v.z, 0.0f); v.w = fmaxf(v.w, 0.0f);
    }
    int sw = nb ^ ((ch >> 2) & 7);
    *(float4*)&tile[ch * 128 + (sw << 2)] = v;
  }
  __syncthreads();

  float acc[4][4] = {};
  float cs[4] = {};
  #pragma unroll
  for (int j = 0; j < 8; ++j) {
    int nblk = wave * 8 + j;
    float4 kr[4], vr[4];
    #pragma unroll
    for (int r = 0; r < 4; ++r) {
      int d = td * 4 + r;
      kr[r] = *(const float4*)&tile[d * 128 + ((nblk ^ td) << 2)];
      int e = 32 + te * 4 + r;
      vr[r] = *(const float4*)&tile[e * 128 + ((nblk ^ te) << 2)];
    }
    #pragma unroll
    for (int r = 0; r < 4; ++r) {
      const float* kp = &kr[r].x;
      cs[r] += kp[0] + kp[1] + kp[2] + kp[3];
      #pragma unroll
      for (int rp = 0; rp < 4; ++rp) {
        const float* vp = &vr[rp].x;
        acc[r][rp] = fmaf(kp[0], vp[0],
                     fmaf(kp[1], vp[1],
                     fmaf(kp[2], vp[2],
                     fmaf(kp[3], vp[3], acc[r][rp]))));
      }
    }
  }
  __syncthreads();   // all tile reads done before red overwrites it

  float* rw = &red[wave * 1056];
  #pragma unroll
  for (int r = 0; r < 4; ++r) {
    #pragma unroll
    for (int rp = 0; rp < 4; ++rp)
      rw[(td * 4 + r) * 33 + te * 4 + rp] = acc[r][rp];
    if (te == 0) rw[(td * 4 + r) * 33 + 32] = cs[r];
  }
  __syncthreads();

  float* cp = ctxbuf + (size_t)(((z * 4 + b) * 16) + head) * 1056;
  for (int i = tid; i < 1056; i += 256) {
    float s = red[i] + red[1056 + i] + red[2112 + i] + red[3168 + i];
    atomic_add_f32(cp + i, s);
  }
}

// Attention phase B -> f16 planes out (feeds proj GEMM only).
__global__ __launch_bounds__(256) void att_apply(
    const float* __restrict__ ctxbuf,
    const float* __restrict__ q0, const float* __restrict__ q0s,
    const float* __restrict__ q1, const float* __restrict__ q1s,
    f16* __restrict__ H)
{
  __shared__ float ctx[1056];
  const int head = blockIdx.x;
  const int b    = blockIdx.y;
  const int tile = blockIdx.z & 15;
  const int z    = blockIdx.z >> 4;
  const int tid  = threadIdx.x;

  const float* cp = ctxbuf + (size_t)(((z * 4 + b) * 16) + head) * 1056;
  for (int i = tid; i < 1056; i += 256) ctx[i] = cp[i];
  __syncthreads();

  const float* qb = (z == 0) ? (head < 8 ? q0 : q0s) : (head < 8 ? q1 : q1s);
  const float* qsrc = qb + ((size_t)b * 256 + (head & 7) * 32) * HW;
  f16* oh = H + (size_t)z * (4 * S_E);
  f16* ol = oh + 2 * S_E;

  const int n = tile * 256 + tid;
  float qv[32];
  #pragma unroll
  for (int d = 0; d < 32; ++d)
    qv[d] = fmaxf(qsrc[(size_t)d * HW + n], 0.0f);
  float den = 1e-15f;
  #pragma unroll
  for (int d = 0; d < 32; ++d)
    den = fmaf(qv[d], ctx[d * 33 + 32], den);
  float rden = 1.0f / den;
  for (int e = 0; e < 32; ++e) {
    float s = 0.0f;
    #pragma unroll
    for (int d = 0; d < 32; ++d)
      s = fmaf(qv[d], ctx[d * 33 + e], s);
    float v = s * rden;
    size_t idx = ((size_t)b * 512 + head * 32 + e) * HW + n;
    f16 h = (f16)v;
    oh[idx] = h;
    ol[idx] = (f16)(v - (float)h);
  }
}

extern "C" void kernel_launch(void* const* d_in, const int* in_sizes, int n_in,
                              void* d_out, int out_size, void* d_ws, size_t ws_size,
                              hipStream_t stream) {
  (void)in_sizes; (void)n_in; (void)out_size; (void)ws_size;
  const float* rgb         = (const float*)d_in[0];
  const float* t           = (const float*)d_in[1];
  const float* m1_inv_w    = (const float*)d_in[2];
  const float* m1_inv_g    = (const float*)d_in[3];
  const float* m1_inv_b    = (const float*)d_in[4];
  const float* m1_dw_w     = (const float*)d_in[5];
  const float* m1_dw_g     = (const float*)d_in[6];
  const float* m1_dw_b     = (const float*)d_in[7];
  const float* m1_pw_w     = (const float*)d_in[8];
  const float* m1_pw_g     = (const float*)d_in[9];
  const float* m1_pw_b     = (const float*)d_in[10];
  const float* kv_w        = (const float*)d_in[11];
  const float* qrgb_w      = (const float*)d_in[12];
  const float* qt_w        = (const float*)d_in[13];
  const float* agg_kv_dw   = (const float*)d_in[14];
  const float* agg_kv_pw   = (const float*)d_in[15];
  const float* agg_t_dw    = (const float*)d_in[16];
  const float* agg_t_pw    = (const float*)d_in[17];
  const float* agg_rgb_dw  = (const float*)d_in[18];
  const float* agg_rgb_pw  = (const float*)d_in[19];
  const float* proj_w      = (const float*)d_in[20];
  const float* m2_inv_w    = (const float*)d_in[21];
  const float* m2_inv_bias = (const float*)d_in[22];
  const float* m2_dw_w     = (const float*)d_in[23];
  const float* m2_dw_bias  = (const float*)d_in[24];
  const float* m2_pw_w     = (const float*)d_in[25];
  const float* m2_pw_g     = (const float*)d_in[26];
  const float* m2_pw_b     = (const float*)d_in[27];
  float* outp = (float*)d_out;

  const size_t S = S_E;
  float* ws = (float*)d_ws;
  f16*   rgbH  = (f16*)(ws + 0 * S);
  f16*   tH    = (f16*)(ws + 1 * S);
  float* s2    = ws + 2 * S;
  f16*   dw1H  = (f16*)(ws + 3 * S);
  float* s3f   = ws + 3 * S;
  f16*   rgbtH = (f16*)(ws + 4 * S);
  float* s4f   = ws + 4 * S;
  float* s5    = ws + 5 * S;
  float* KV    = ws + 6 * S;
  f16*   attH  = (f16*)(ws + 6 * S);
  float* KVS   = ws + 10 * S;
  float* CTX   = ws + 14 * S;
  float* WB    = ws + 14 * S + 150016;
  f16*   projH = (f16*)(ws + 15 * S);

  f16* wb = (f16*)WB;
  f16* w_m1inv = wb;
  f16* w_m1pw  = wb + 262144;
  f16* w_kv    = wb + 393216;
  f16* w_qt    = wb + 917504;
  f16* w_qrgb  = wb + 1048576;
  f16* w_proj  = wb + 1179648;
  f16* w_m2inv = wb + 1703936;
  f16* w_m2pw  = wb + 2228224;

  dim3 blk(256);
  const int XN4 = (int)(S_E / 4);

  cvt_planes<<<dim3(4096), blk, 0, stream>>>(rgb, rgbH, rgbH + S_E, XN4);
  cvt_planes<<<dim3(4096), blk, 0, stream>>>(t,   tH,   tH   + S_E, XN4);
  // weights -> fragment-ordered hi/lo planes
  cvt_wfrag<<<dim3(64),  blk, 0, stream>>>(m1_inv_w, w_m1inv, w_m1inv + 131072, 512, 16384);
  cvt_wfrag<<<dim3(32),  blk, 0, stream>>>(m1_pw_w,  w_m1pw,  w_m1pw  + 65536,  256, 8192);
  cvt_wfrag<<<dim3(128), blk, 0, stream>>>(kv_w,     w_kv,    w_kv    + 262144, 256, 32768);
  cvt_wfrag<<<dim3(32),  blk, 0, stream>>>(qt_w,     w_qt,    w_qt    + 65536,  256, 8192);
  cvt_wfrag<<<dim3(32),  blk, 0, stream>>>(qrgb_w,   w_qrgb,  w_qrgb  + 65536,  256, 8192);
  cvt_wfrag<<<dim3(128), blk, 0, stream>>>(proj_w,   w_proj,  w_proj  + 262144, 1024, 32768);
  cvt_wfrag<<<dim3(128), blk, 0, stream>>>(m2_inv_w, w_m2inv, w_m2inv + 262144, 256, 32768);
  cvt_wfrag<<<dim3(128), blk, 0, stream>>>(m2_pw_w,  w_m2pw,  w_m2pw  + 262144, 1024, 32768);

  // m1 stem
  gemm_mfma<64><<<dim3(64, 2, 4), blk, 0, stream>>>(
      rgbH, rgbH + S_E, tH, tH + S_E, w_m1inv, w_m1inv + 131072,
      s2, nullptr, nullptr, m1_inv_g, m1_inv_b, 512, 256, 256, 2);
  dwconv3<<<dim3(1024), blk, 0, stream>>>(
      s2, m1_dw_w, nullptr, dw1H, dw1H + S_E, m1_dw_g, m1_dw_b, 255, 2, 1);
  gemm_mfma<64><<<dim3(64, 2, 4), blk, 0, stream>>>(
      dw1H, dw1H + S_E, dw1H, dw1H + S_E, w_m1pw, w_m1pw + 65536,
      nullptr, rgbtH, rgbtH + S_E, m1_pw_g, m1_pw_b, 256, 256, 256, 1);

  // projections
  gemm_mfma<64><<<dim3(64, 8, 4), blk, 0, stream>>>(
      rgbtH, rgbtH + S_E, rgbtH, rgbtH + S_E, w_kv, w_kv + 262144,
      KV, nullptr, nullptr, nullptr, nullptr, 256, 256, 1024, 0);
  gemm_mfma<64><<<dim3(64, 2, 4), blk, 0, stream>>>(
      tH, tH + S_E, tH, tH + S_E, w_qt, w_qt + 65536,
      s2, nullptr, nullptr, nullptr, nullptr, 256, 256, 256, 0);
  gemm_mfma<64><<<dim3(64, 2, 4), blk, 0, stream>>>(
      rgbH, rgbH + S_E, rgbH, rgbH + S_E, w_qrgb, w_qrgb + 65536,
      s5, nullptr, nullptr, nullptr, nullptr, 256, 256, 256, 0);

  // multi-scale aggregation (weights via scalar path, image tile in LDS)
  agg_fused<8><<<dim3(32, 4, 8),  blk, 0, stream>>>(KV, agg_kv_dw, agg_kv_pw, KVS, 1024);
  agg_fused<4><<<dim3(8, 4, 16),  blk, 0, stream>>>(s2, agg_t_dw,  agg_t_pw,  s3f, 256);
  agg_fused<4><<<dim3(8, 4, 16),  blk, 0, stream>>>(s5, agg_rgb_dw, agg_rgb_pw, s4f, 256);

  // attention
  zero_buf4<<<dim3(132), blk, 0, stream>>>((float4*)CTX, 128 * 264);
  att_ctx<<<dim3(16, 4, 64), blk, 0, stream>>>(KV, KVS, CTX);
  att_apply<<<dim3(16, 4, 32), blk, 0, stream>>>(CTX, s2, s3f, s5, s4f, attH);

  // proj + m2 tail
  gemm_mfma<64><<<dim3(64, 2, 4), blk, 0, stream>>>(
      attH, attH + 2 * S_E, attH + 4 * S_E, attH + 6 * S_E, w_proj, w_proj + 262144,
      nullptr, projH, projH + S_E, nullptr, nullptr, 1024, 512, 256, 0);
  gemm_mfma<64><<<dim3(64, 8, 4), blk, 0, stream>>>(
      projH, projH + S_E, projH, projH + S_E, w_m2inv, w_m2inv + 262144,
      KVS, nullptr, nullptr, nullptr, m2_inv_bias, 256, 256, 1024, 3);
  dwconv3<<<dim3(4096), blk, 0, stream>>>(
      KVS, m2_dw_w, nullptr, (f16*)(ws + 6 * S), (f16*)(ws + 8 * S),
      nullptr, m2_dw_bias, 1023, 3, 1);
  gemm_mfma<64><<<dim3(64, 2, 4), blk, 0, stream>>>(
      (f16*)(ws + 6 * S), (f16*)(ws + 8 * S), (f16*)(ws + 6 * S), (f16*)(ws + 8 * S),
      w_m2pw, w_m2pw + 262144,
      outp, nullptr, nullptr, m2_pw_g, m2_pw_b, 1024, 1024, 256, 1);
}

// Round 12
// 676.726 us; speedup vs baseline: 1.2894x; 1.2894x over previous
//
#include <hip/hip_runtime.h>

#define HW 4096
#define S_E ((size_t)4 * 256 * 4096)   // elems in one (B,256,64,64) tensor

using f16   = _Float16;
using f16x8 = __attribute__((ext_vector_type(8))) _Float16;
using f32x4 = __attribute__((ext_vector_type(4))) float;

__device__ __forceinline__ float hswish(float x) {
  float r = fminf(fmaxf(x + 3.0f, 0.0f), 6.0f);
  return x * r * (1.0f / 6.0f);
}

__device__ __forceinline__ void atomic_add_f32(float* p, float v) {
  __hip_atomic_fetch_add(p, v, __ATOMIC_RELAXED, __HIP_MEMORY_SCOPE_AGENT);
}

__global__ __launch_bounds__(256) void zero_buf4(float4* __restrict__ p, int n4) {
  int i = blockIdx.x * 256 + threadIdx.x;
  if (i < n4) p[i] = make_float4(0.f, 0.f, 0.f, 0.f);
}

// fp32 -> f16 hi/lo planes (x = hi + lo, ~22 significand bits)
__global__ __launch_bounds__(256) void cvt_planes(
    const float* __restrict__ in, f16* __restrict__ hi, f16* __restrict__ lo, int n4)
{
  int i = blockIdx.x * 256 + threadIdx.x;
  if (i >= n4) return;
  float4 v = ((const float4*)in)[i];
  const float* f = &v.x;
  unsigned int hw[2], lw[2];
  #pragma unroll
  for (int j = 0; j < 2; ++j) {
    f16 h0 = (f16)f[2 * j], h1 = (f16)f[2 * j + 1];
    f16 l0 = (f16)(f[2 * j] - (float)h0), l1 = (f16)(f[2 * j + 1] - (float)h1);
    hw[j] = (unsigned int)__builtin_bit_cast(unsigned short, h0) |
            ((unsigned int)__builtin_bit_cast(unsigned short, h1) << 16);
    lw[j] = (unsigned int)__builtin_bit_cast(unsigned short, l0) |
            ((unsigned int)__builtin_bit_cast(unsigned short, l1) << 16);
  }
  *(uint2*)(hi + 4 * (size_t)i) = make_uint2(hw[0], hw[1]);
  *(uint2*)(lo + 4 * (size_t)i) = make_uint2(lw[0], lw[1]);
}

// fp32 weights [CO][K] -> MFMA-fragment-ordered hi/lo planes:
// chunk g = (ct*(K/32) + kq)*64 + lane holds w[ct*16 + (lane&15)][kq*32 + (lane>>4)*8 + 0..7].
// In the GEMM, a wave's fragment load becomes base + lane*16B -> one contiguous 1KB burst.
__global__ __launch_bounds__(256) void cvt_wfrag(
    const float* __restrict__ in, f16* __restrict__ hi, f16* __restrict__ lo,
    int K, int nch)
{
  int g = blockIdx.x * 256 + threadIdx.x;
  if (g >= nch) return;
  int lane = g & 63;
  int kq   = (g >> 6) % (K >> 5);
  int ct   = g / ((K >> 5) << 6);
  const float* src = in + (size_t)(ct * 16 + (lane & 15)) * K
                        + kq * 32 + (lane >> 4) * 8;
  unsigned short hv[8], lv[8];
  #pragma unroll
  for (int j = 0; j < 8; ++j) {
    float v = src[j];
    f16 h = (f16)v;
    hv[j] = __builtin_bit_cast(unsigned short, h);
    lv[j] = __builtin_bit_cast(unsigned short, (f16)(v - (float)h));
  }
  *(uint4*)(hi + (size_t)g * 8) = *(const uint4*)hv;
  *(uint4*)(lo + (size_t)g * 8) = *(const uint4*)lv;
}

// f16x3 split MFMA 1x1-conv GEMM — R8 version (fragment-ordered weights), KS=64.
template<int KS>
__global__ __launch_bounds__(256) void gemm_mfma(
    const f16* __restrict__ xhi0, const f16* __restrict__ xlo0,
    const f16* __restrict__ xhi1, const f16* __restrict__ xlo1,
    const f16* __restrict__ whi, const f16* __restrict__ wlo,
    float* __restrict__ out, f16* __restrict__ ohi, f16* __restrict__ olo,
    const float* __restrict__ scale, const float* __restrict__ bias,
    int K, int k0, int CO, int epi)
{
  constexpr int ST = KS + 4;       // f16 row stride in LDS
  constexpr int NC = KS / 32;      // 32-k chunks per staged step
  __shared__ f16 Bh[64 * ST];
  __shared__ f16 Bl[64 * ST];
  const int p0  = blockIdx.x * 64;
  const int co0 = blockIdx.y * 128;
  const int b   = blockIdx.z;
  const int tid = threadIdx.x;
  const int lane = tid & 63;
  const int wave = tid >> 6;
  const int wc = wave & 1, wp = wave >> 1;
  const int k1 = K - k0;

  const int tt    = tid & 127;
  const int kbase = (tt >> 3) * 2;
  const int poct  = (tt & 7) * 8;
  const f16* x0 = (tid < 128) ? xhi0 : xlo0;
  const f16* x1 = (tid < 128) ? xhi1 : xlo1;
  f16* Bp = (tid < 128) ? Bh : Bl;

  const int q  = lane >> 4;
  const int ln = lane & 15;
  const int kq5 = K >> 5;                       // K/32
  const int ctb = (co0 >> 4) + wc * 4;          // fragment row-tile base

  f32x4 acc[4][2];
  #pragma unroll
  for (int im = 0; im < 4; ++im)
    #pragma unroll
    for (int in = 0; in < 2; ++in)
      acc[im][in] = (f32x4){0.f, 0.f, 0.f, 0.f};

  auto gaddr = [&](int kg) -> const f16* {
    return (kg < k0) ? x0 + ((size_t)b * k0 + kg) * HW
                     : x1 + ((size_t)b * k1 + (kg - k0)) * HW;
  };

  uint4 g0[NC], g1[NC];
  #pragma unroll
  for (int c = 0; c < NC; ++c) {
    const f16* x = gaddr(c * 32 + kbase);
    g0[c] = *(const uint4*)(x + p0 + poct);
    g1[c] = *(const uint4*)(x + HW + p0 + poct);
  }

  for (int kt = 0; kt < K; kt += KS) {
    #pragma unroll
    for (int c = 0; c < NC; ++c) {
      const unsigned short* u0 = (const unsigned short*)&g0[c];
      const unsigned short* u1 = (const unsigned short*)&g1[c];
      #pragma unroll
      for (int i = 0; i < 8; ++i) {
        unsigned int d = (unsigned int)u0[i] | ((unsigned int)u1[i] << 16);
        *(unsigned int*)(Bp + (poct + i) * ST + c * 32 + kbase) = d;
      }
    }
    __syncthreads();
    if (kt + KS < K) {
      #pragma unroll
      for (int c = 0; c < NC; ++c) {
        const f16* x = gaddr(kt + KS + c * 32 + kbase);
        g0[c] = *(const uint4*)(x + p0 + poct);
        g1[c] = *(const uint4*)(x + HW + p0 + poct);
      }
    }
    #pragma unroll
    for (int c = 0; c < NC; ++c) {
      f16x8 bh[2], bl[2];
      #pragma unroll
      for (int in = 0; in < 2; ++in) {
        const f16* fp = &Bh[(wp * 32 + in * 16 + ln) * ST + c * 32 + q * 8];
        const f16* gp = &Bl[(wp * 32 + in * 16 + ln) * ST + c * 32 + q * 8];
        ((uint2*)&bh[in])[0] = *(const uint2*)fp;
        ((uint2*)&bh[in])[1] = *(const uint2*)(fp + 4);
        ((uint2*)&bl[in])[0] = *(const uint2*)gp;
        ((uint2*)&bl[in])[1] = *(const uint2*)(gp + 4);
      }
      const int kq = (kt + c * 32) >> 5;
      #pragma unroll
      for (int im = 0; im < 4; ++im) {
        size_t wofs = (((size_t)(ctb + im) * kq5 + kq) << 9) + lane * 8;
        f16x8 ah = *(const f16x8*)(whi + wofs);
        f16x8 al = *(const f16x8*)(wlo + wofs);
        #pragma unroll
        for (int in = 0; in < 2; ++in) {
          acc[im][in] = __builtin_amdgcn_mfma_f32_16x16x32_f16(ah, bh[in], acc[im][in], 0, 0, 0);
          acc[im][in] = __builtin_amdgcn_mfma_f32_16x16x32_f16(ah, bl[in], acc[im][in], 0, 0, 0);
          acc[im][in] = __builtin_amdgcn_mfma_f32_16x16x32_f16(al, bh[in], acc[im][in], 0, 0, 0);
        }
      }
    }
    __syncthreads();
  }

  #pragma unroll
  for (int im = 0; im < 4; ++im) {
    #pragma unroll
    for (int in = 0; in < 2; ++in) {
      int p = p0 + wp * 32 + in * 16 + ln;
      #pragma unroll
      for (int r = 0; r < 4; ++r) {
        int co = co0 + wc * 64 + im * 16 + q * 4 + r;
        float v = acc[im][in][r];
        if (epi == 1)      v = v * scale[co] + bias[co];
        else if (epi == 2) v = hswish(v * scale[co] + bias[co]);
        else if (epi == 3) v = hswish(v + bias[co]);
        size_t idx = ((size_t)b * CO + co) * HW + p;
        if (out) out[idx] = v;
        else {
          f16 h = (f16)v;
          ohi[idx] = h;
          olo[idx] = (f16)(v - (float)h);
        }
      }
    }
  }
}

// LDS-tiled depthwise 3x3, pad 1. One block per (b,c). pmode 1 -> f16 planes out.
__global__ __launch_bounds__(256) void dwconv3(
    const float* __restrict__ in, const float* __restrict__ w,
    float* __restrict__ out, f16* __restrict__ ohi, f16* __restrict__ olo,
    const float* __restrict__ scale, const float* __restrict__ bias,
    int Cmask, int epi, int pmode)
{
  __shared__ float tl[66 * 66];
  const int bc = blockIdx.x;
  const int c  = bc & Cmask;
  const float* src = in + (size_t)bc * HW;
  const int t = threadIdx.x;
  for (int i = t; i < 66 * 66; i += 256) {
    int r = i / 66, cc = i - r * 66;
    int gy = r - 1, gx = cc - 1;
    float v = 0.0f;
    if (gy >= 0 && gy < 64 && gx >= 0 && gx < 64) v = src[(gy << 6) + gx];
    tl[i] = v;
  }
  const float* wp = w + c * 9;
  float w00 = wp[0], w01 = wp[1], w02 = wp[2];
  float w10 = wp[3], w11 = wp[4], w12 = wp[5];
  float w20 = wp[6], w21 = wp[7], w22 = wp[8];
  float g = (epi == 2) ? scale[c] : 1.0f;
  float bb = bias[c];
  __syncthreads();
  #pragma unroll 4
  for (int j = 0; j < 16; ++j) {
    int p = j * 256 + t;
    int y = p >> 6, x = p & 63;
    const float* bp = &tl[y * 66 + x];
    float s;
    s = w00 * bp[0]        + w01 * bp[1]        + w02 * bp[2];
    s = fmaf(w10, bp[66],    fmaf(w11, bp[67],    fmaf(w12, bp[68],  s)));
    s = fmaf(w20, bp[132],   fmaf(w21, bp[133],   fmaf(w22, bp[134], s)));
    float v = (epi == 2) ? hswish(s * g + bb) : hswish(s + bb);
    size_t idx = (size_t)bc * HW + p;
    if (pmode) {
      f16 h = (f16)v;
      ohi[idx] = h;
      olo[idx] = (f16)(v - (float)h);
    } else {
      out[idx] = v;
    }
  }
}

// Fused dw5x5(pad2) + grouped 1x1 (32->32 per group).
// R10: weights read directly from global (wave-uniform -> scalar path).
template<int TR>
__global__ __launch_bounds__(256) void agg_fused(
    const float* __restrict__ in, const float* __restrict__ dw,
    const float* __restrict__ pw, float* __restrict__ out, int C)
{
  constexpr int RH = TR + 4;            // tile rows incl. halo
  constexpr int NR = TR / 4;            // row-sets per thread
  __shared__ float in_t[8 * RH * 68];
  const int g = blockIdx.x, b = blockIdx.y, tile = blockIdx.z;
  const int t = threadIdx.x;
  const int y0 = tile * TR;
  const float* src = in + ((size_t)b * C + g * 32) * HW;
  const float* dwg = dw + (size_t)g * 800;
  const float* pwg = pw + (size_t)g * 1024;

  const int x = t & 63, yl = t >> 6;
  float acc[NR][32] = {};

  for (int ph = 0; ph < 4; ++ph) {
    __syncthreads();
    constexpr int T4 = 8 * RH * 16;
    for (int i = t; i < T4; i += 256) {
      int qq = i & 15;
      int rid = i >> 4;
      int ch = rid / RH, r = rid - ch * RH;
      int gy = y0 - 2 + r;
      float4 v = make_float4(0.f, 0.f, 0.f, 0.f);
      if (gy >= 0 && gy < 64)
        v = *(const float4*)(src + (size_t)(ph * 8 + ch) * HW + (gy << 6) + (qq << 2));
      *(float4*)&in_t[(ch * RH + r) * 68 + 2 + (qq << 2)] = v;
    }
    for (int i = t; i < 8 * RH * 4; i += 256) {
      int side = i & 3;
      int rid = i >> 2;
      int col = (side < 2) ? side : 64 + side;
      in_t[rid * 68 + col] = 0.0f;
    }
    __syncthreads();
    for (int cl = 0; cl < 8; ++cl) {
      int ci = ph * 8 + cl;
      const float* bp = &in_t[(cl * RH) * 68 + 2 + x];
      const float* wv = dwg + ci * 25;           // uniform addr -> s_load
      float d[NR] = {};
      #pragma unroll
      for (int k = 0; k < 25; ++k) {
        int dy = k / 5, dx = (k % 5) - 2;
        float w = wv[k];
        #pragma unroll
        for (int r = 0; r < NR; ++r)
          d[r] = fmaf(w, bp[(yl + r * 4 + dy) * 68 + dx], d[r]);
      }
      #pragma unroll
      for (int m = 0; m < 32; ++m) {
        float w = pwg[m * 32 + ci];              // uniform addr -> s_load
        #pragma unroll
        for (int r = 0; r < NR; ++r)
          acc[r][m] = fmaf(w, d[r], acc[r][m]);
      }
    }
  }
  float* dst = out + ((size_t)b * C + g * 32) * HW + y0 * 64;
  #pragma unroll
  for (int m = 0; m < 32; ++m) {
    #pragma unroll
    for (int r = 0; r < NR; ++r)
      dst[(size_t)m * HW + ((yl + r * 4) << 6) + x] = acc[r][m];
  }
}

// Attention phase A. R12: LDS aliasing kept (red overlays tile, 32 KB), the
// R11 forced launch bound REMOVED (it caused ~570MB of scratch spills).
// Register diet in source instead: kr staged per-r (saves ~12 live VGPRs,
// target <=128 naturally -> 4 waves/SIMD, no spills). Per-acc fmaf chain
// order unchanged -> bit-identical numerics.
__global__ __launch_bounds__(256) void att_ctx(
    const float* __restrict__ kv, const float* __restrict__ kvs,
    float* __restrict__ ctxbuf)
{
  __shared__ float tile[64 * 128];   // staging; reused as red[4*1056] after compute
  float* red = tile;
  const int head  = blockIdx.x;
  const int b     = blockIdx.y;
  const int slice = blockIdx.z & 31;
  const int z     = blockIdx.z >> 5;
  const int tid   = threadIdx.x;
  const int lane  = tid & 63;
  const int wave  = tid >> 6;
  const int td = lane & 7, te = lane >> 3;

  const float* kvsrc = (head < 8)
      ? kv  + ((size_t)b * 1024 + z * 512 + head * 64) * HW
      : kvs + ((size_t)b * 1024 + z * 512 + (head - 8) * 64) * HW;
  const int n0 = slice * 128;

  #pragma unroll
  for (int j = 0; j < 8; ++j) {
    int slot = j * 256 + tid;          // 2048 float4 slots
    int ch = slot >> 5;                // 32 blocks per row
    int nb = slot & 31;
    float4 v = *(const float4*)(kvsrc + (size_t)ch * HW + n0 + (nb << 2));
    if (ch < 32) {
      v.x = fmaxf(v.x, 0.0f); v.y = fmaxf(v.y, 0.0f);
      v.z = fmaxf(v.z, 0.0f); v.w = fmaxf(v.w, 0.0f);
    }
    int sw = nb ^ ((ch >> 2) & 7);
    *(float4*)&tile[ch * 128 + (sw << 2)] = v;
  }
  __syncthreads();

  float acc[4][4] = {};
  float cs[4] = {};
  #pragma unroll
  for (int j = 0; j < 8; ++j) {
    int nblk = wave * 8 + j;
    float4 vr[4];
    #pragma unroll
    for (int r = 0; r < 4; ++r) {
      int e = 32 + te * 4 + r;                  // (e>>2)&7 == te
      vr[r] = *(const float4*)&tile[e * 128 + ((nblk ^ te) << 2)];
    }
    #pragma unroll
    for (int r = 0; r < 4; ++r) {
      int d = td * 4 + r;                       // (d>>2)&7 == td
      float4 kr = *(const float4*)&tile[d * 128 + ((nblk ^ td) << 2)];
      const float* kp = &kr.x;
      cs[r] += kp[0] + kp[1] + kp[2] + kp[3];
      #pragma unroll
      for (int rp = 0; rp < 4; ++rp) {
        const float* vp = &vr[rp].x;
        acc[r][rp] = fmaf(kp[0], vp[0],
                     fmaf(kp[1], vp[1],
                     fmaf(kp[2], vp[2],
                     fmaf(kp[3], vp[3], acc[r][rp]))));
      }
    }
  }
  __syncthreads();   // all tile reads done before red overwrites it

  float* rw = &red[wave * 1056];
  #pragma unroll
  for (int r = 0; r < 4; ++r) {
    #pragma unroll
    for (int rp = 0; rp < 4; ++rp)
      rw[(td * 4 + r) * 33 + te * 4 + rp] = acc[r][rp];
    if (te == 0) rw[(td * 4 + r) * 33 + 32] = cs[r];
  }
  __syncthreads();

  float* cp = ctxbuf + (size_t)(((z * 4 + b) * 16) + head) * 1056;
  for (int i = tid; i < 1056; i += 256) {
    float s = red[i] + red[1056 + i] + red[2112 + i] + red[3168 + i];
    atomic_add_f32(cp + i, s);
  }
}

// Attention phase B -> f16 planes out (feeds proj GEMM only).
__global__ __launch_bounds__(256) void att_apply(
    const float* __restrict__ ctxbuf,
    const float* __restrict__ q0, const float* __restrict__ q0s,
    const float* __restrict__ q1, const float* __restrict__ q1s,
    f16* __restrict__ H)
{
  __shared__ float ctx[1056];
  const int head = blockIdx.x;
  const int b    = blockIdx.y;
  const int tile = blockIdx.z & 15;
  const int z    = blockIdx.z >> 4;
  const int tid  = threadIdx.x;

  const float* cp = ctxbuf + (size_t)(((z * 4 + b) * 16) + head) * 1056;
  for (int i = tid; i < 1056; i += 256) ctx[i] = cp[i];
  __syncthreads();

  const float* qb = (z == 0) ? (head < 8 ? q0 : q0s) : (head < 8 ? q1 : q1s);
  const float* qsrc = qb + ((size_t)b * 256 + (head & 7) * 32) * HW;
  f16* oh = H + (size_t)z * (4 * S_E);
  f16* ol = oh + 2 * S_E;

  const int n = tile * 256 + tid;
  float qv[32];
  #pragma unroll
  for (int d = 0; d < 32; ++d)
    qv[d] = fmaxf(qsrc[(size_t)d * HW + n], 0.0f);
  float den = 1e-15f;
  #pragma unroll
  for (int d = 0; d < 32; ++d)
    den = fmaf(qv[d], ctx[d * 33 + 32], den);
  float rden = 1.0f / den;
  for (int e = 0; e < 32; ++e) {
    float s = 0.0f;
    #pragma unroll
    for (int d = 0; d < 32; ++d)
      s = fmaf(qv[d], ctx[d * 33 + e], s);
    float v = s * rden;
    size_t idx = ((size_t)b * 512 + head * 32 + e) * HW + n;
    f16 h = (f16)v;
    oh[idx] = h;
    ol[idx] = (f16)(v - (float)h);
  }
}

extern "C" void kernel_launch(void* const* d_in, const int* in_sizes, int n_in,
                              void* d_out, int out_size, void* d_ws, size_t ws_size,
                              hipStream_t stream) {
  (void)in_sizes; (void)n_in; (void)out_size; (void)ws_size;
  const float* rgb         = (const float*)d_in[0];
  const float* t           = (const float*)d_in[1];
  const float* m1_inv_w    = (const float*)d_in[2];
  const float* m1_inv_g    = (const float*)d_in[3];
  const float* m1_inv_b    = (const float*)d_in[4];
  const float* m1_dw_w     = (const float*)d_in[5];
  const float* m1_dw_g     = (const float*)d_in[6];
  const float* m1_dw_b     = (const float*)d_in[7];
  const float* m1_pw_w     = (const float*)d_in[8];
  const float* m1_pw_g     = (const float*)d_in[9];
  const float* m1_pw_b     = (const float*)d_in[10];
  const float* kv_w        = (const float*)d_in[11];
  const float* qrgb_w      = (const float*)d_in[12];
  const float* qt_w        = (const float*)d_in[13];
  const float* agg_kv_dw   = (const float*)d_in[14];
  const float* agg_kv_pw   = (const float*)d_in[15];
  const float* agg_t_dw    = (const float*)d_in[16];
  const float* agg_t_pw    = (const float*)d_in[17];
  const float* agg_rgb_dw  = (const float*)d_in[18];
  const float* agg_rgb_pw  = (const float*)d_in[19];
  const float* proj_w      = (const float*)d_in[20];
  const float* m2_inv_w    = (const float*)d_in[21];
  const float* m2_inv_bias = (const float*)d_in[22];
  const float* m2_dw_w     = (const float*)d_in[23];
  const float* m2_dw_bias  = (const float*)d_in[24];
  const float* m2_pw_w     = (const float*)d_in[25];
  const float* m2_pw_g     = (const float*)d_in[26];
  const float* m2_pw_b     = (const float*)d_in[27];
  float* outp = (float*)d_out;

  const size_t S = S_E;
  float* ws = (float*)d_ws;
  f16*   rgbH  = (f16*)(ws + 0 * S);
  f16*   tH    = (f16*)(ws + 1 * S);
  float* s2    = ws + 2 * S;
  f16*   dw1H  = (f16*)(ws + 3 * S);
  float* s3f   = ws + 3 * S;
  f16*   rgbtH = (f16*)(ws + 4 * S);
  float* s4f   = ws + 4 * S;
  float* s5    = ws + 5 * S;
  float* KV    = ws + 6 * S;
  f16*   attH  = (f16*)(ws + 6 * S);
  float* KVS   = ws + 10 * S;
  float* CTX   = ws + 14 * S;
  float* WB    = ws + 14 * S + 150016;
  f16*   projH = (f16*)(ws + 15 * S);

  f16* wb = (f16*)WB;
  f16* w_m1inv = wb;
  f16* w_m1pw  = wb + 262144;
  f16* w_kv    = wb + 393216;
  f16* w_qt    = wb + 917504;
  f16* w_qrgb  = wb + 1048576;
  f16* w_proj  = wb + 1179648;
  f16* w_m2inv = wb + 1703936;
  f16* w_m2pw  = wb + 2228224;

  dim3 blk(256);
  const int XN4 = (int)(S_E / 4);

  cvt_planes<<<dim3(4096), blk, 0, stream>>>(rgb, rgbH, rgbH + S_E, XN4);
  cvt_planes<<<dim3(4096), blk, 0, stream>>>(t,   tH,   tH   + S_E, XN4);
  // weights -> fragment-ordered hi/lo planes
  cvt_wfrag<<<dim3(64),  blk, 0, stream>>>(m1_inv_w, w_m1inv, w_m1inv + 131072, 512, 16384);
  cvt_wfrag<<<dim3(32),  blk, 0, stream>>>(m1_pw_w,  w_m1pw,  w_m1pw  + 65536,  256, 8192);
  cvt_wfrag<<<dim3(128), blk, 0, stream>>>(kv_w,     w_kv,    w_kv    + 262144, 256, 32768);
  cvt_wfrag<<<dim3(32),  blk, 0, stream>>>(qt_w,     w_qt,    w_qt    + 65536,  256, 8192);
  cvt_wfrag<<<dim3(32),  blk, 0, stream>>>(qrgb_w,   w_qrgb,  w_qrgb  + 65536,  256, 8192);
  cvt_wfrag<<<dim3(128), blk, 0, stream>>>(proj_w,   w_proj,  w_proj  + 262144, 1024, 32768);
  cvt_wfrag<<<dim3(128), blk, 0, stream>>>(m2_inv_w, w_m2inv, w_m2inv + 262144, 256, 32768);
  cvt_wfrag<<<dim3(128), blk, 0, stream>>>(m2_pw_w,  w_m2pw,  w_m2pw  + 262144, 1024, 32768);

  // m1 stem
  gemm_mfma<64><<<dim3(64, 2, 4), blk, 0, stream>>>(
      rgbH, rgbH + S_E, tH, tH + S_E, w_m1inv, w_m1inv + 131072,
      s2, nullptr, nullptr, m1_inv_g, m1_inv_b, 512, 256, 256, 2);
  dwconv3<<<dim3(1024), blk, 0, stream>>>(
      s2, m1_dw_w, nullptr, dw1H, dw1H + S_E, m1_dw_g, m1_dw_b, 255, 2, 1);
  gemm_mfma<64><<<dim3(64, 2, 4), blk, 0, stream>>>(
      dw1H, dw1H + S_E, dw1H, dw1H + S_E, w_m1pw, w_m1pw + 65536,
      nullptr, rgbtH, rgbtH + S_E, m1_pw_g, m1_pw_b, 256, 256, 256, 1);

  // projections
  gemm_mfma<64><<<dim3(64, 8, 4), blk, 0, stream>>>(
      rgbtH, rgbtH + S_E, rgbtH, rgbtH + S_E, w_kv, w_kv + 262144,
      KV, nullptr, nullptr, nullptr, nullptr, 256, 256, 1024, 0);
  gemm_mfma<64><<<dim3(64, 2, 4), blk, 0, stream>>>(
      tH, tH + S_E, tH, tH + S_E, w_qt, w_qt + 65536,
      s2, nullptr, nullptr, nullptr, nullptr, 256, 256, 256, 0);
  gemm_mfma<64><<<dim3(64, 2, 4), blk, 0, stream>>>(
      rgbH, rgbH + S_E, rgbH, rgbH + S_E, w_qrgb, w_qrgb + 65536,
      s5, nullptr, nullptr, nullptr, nullptr, 256, 256, 256, 0);

  // multi-scale aggregation (weights via scalar path, image tile in LDS)
  agg_fused<8><<<dim3(32, 4, 8),  blk, 0, stream>>>(KV, agg_kv_dw, agg_kv_pw, KVS, 1024);
  agg_fused<4><<<dim3(8, 4, 16),  blk, 0, stream>>>(s2, agg_t_dw,  agg_t_pw,  s3f, 256);
  agg_fused<4><<<dim3(8, 4, 16),  blk, 0, stream>>>(s5, agg_rgb_dw, agg_rgb_pw, s4f, 256);

  // attention
  zero_buf4<<<dim3(132), blk, 0, stream>>>((float4*)CTX, 128 * 264);
  att_ctx<<<dim3(16, 4, 64), blk, 0, stream>>>(KV, KVS, CTX);
  att_apply<<<dim3(16, 4, 32), blk, 0, stream>>>(CTX, s2, s3f, s5, s4f, attH);

  // proj + m2 tail
  gemm_mfma<64><<<dim3(64, 2, 4), blk, 0, stream>>>(
      attH, attH + 2 * S_E, attH + 4 * S_E, attH + 6 * S_E, w_proj, w_proj + 262144,
      nullptr, projH, projH + S_E, nullptr, nullptr, 1024, 512, 256, 0);
  gemm_mfma<64><<<dim3(64, 8, 4), blk, 0, stream>>>(
      projH, projH + S_E, projH, projH + S_E, w_m2inv, w_m2inv + 262144,
      KVS, nullptr, nullptr, nullptr, m2_inv_bias, 256, 256, 1024, 3);
  dwconv3<<<dim3(4096), blk, 0, stream>>>(
      KVS, m2_dw_w, nullptr, (f16*)(ws + 6 * S), (f16*)(ws + 8 * S),
      nullptr, m2_dw_bias, 1023, 3, 1);
  gemm_mfma<64><<<dim3(64, 2, 4), blk, 0, stream>>>(
      (f16*)(ws + 6 * S), (f16*)(ws + 8 * S), (f16*)(ws + 6 * S), (f16*)(ws + 8 * S),
      w_m2pw, w_m2pw + 262144,
      outp, nullptr, nullptr, m2_pw_g, m2_pw_b, 1024, 1024, 256, 1);
}